// Round 5
// baseline (1016.425 us; speedup 1.0000x reference)
//
#include <hip/hip_runtime.h>
#include <hip/hip_bf16.h>
#include <math.h>

typedef unsigned short u16;
typedef __bf16 bf16x8 __attribute__((ext_vector_type(8)));
typedef float f32x4 __attribute__((ext_vector_type(4)));

__device__ __forceinline__ float b2f(u16 u) {
  union { unsigned int i; float f; } v; v.i = ((unsigned int)u) << 16; return v.f;
}
__device__ __forceinline__ u16 f2b(float f) {
  union { float f; unsigned int i; } v; v.f = f;
  unsigned int x = v.i;
  return (u16)((x + 0x7fffu + ((x >> 16) & 1u)) >> 16);
}
__device__ __forceinline__ float ldx(const void* p, size_t i, int isf) {
  return isf ? ((const float*)p)[i] : b2f(((const u16*)p)[i]);
}

// ---------------- kernel 0: dtype detect (f32 vs bf16) ----------------
__global__ void k_detect(const void* __restrict__ query, int* __restrict__ flag) {
  int t = threadIdx.x;  // 64 threads
  float v = ((const float*)query)[t];
  int ok = (v == v && fabsf(v) < 100.f && fabsf(v) > 1e-4f) ? 1 : 0;
  unsigned long long m = __ballot(ok);
  if (t == 0) flag[0] = (__popcll(m) >= 32) ? 1 : 0;
}

// ---------------- kernel 1: LDS-tiled transpose W_in -> bf16 WT[j][c] ----------------
__global__ __launch_bounds__(256) void k_transpose(const void* __restrict__ Win,
                                                   u16* __restrict__ WT,
                                                   const int* __restrict__ flag) {
  int isf = flag[0];
  __shared__ float ts[64 * 65];
  int blk = blockIdx.x;           // 64 tiles: 8x8
  int j0 = (blk & 7) * 64, c0 = (blk >> 3) * 64;
  int t = threadIdx.x;
  #pragma unroll
  for (int k = 0; k < 16; k++) {
    int e = t + 256 * k;          // 4096 elems
    int cl = e >> 6, jl = e & 63;
    ts[cl * 65 + jl] = ldx(Win, (size_t)(c0 + cl) * 512 + j0 + jl, isf);
  }
  __syncthreads();
  #pragma unroll
  for (int k = 0; k < 16; k++) {
    int e = t + 256 * k;
    int jl = e >> 6, cl = e & 63;
    WT[(size_t)(j0 + jl) * 512 + c0 + cl] = f2b(ts[cl * 65 + jl]);
  }
}

// ---------------- kernel 2a: qln[b][c] = LN(query)*g_q + be_q ----------------
__global__ __launch_bounds__(512) void k_qln(
    const void* __restrict__ query, const void* __restrict__ g_q, const void* __restrict__ be_q,
    float* __restrict__ qln, const int* __restrict__ flag) {
  int isf = flag[0];
  int b = blockIdx.x, t = threadIdx.x;
  __shared__ float red[16];
  __shared__ float stats[2];
  float v = ldx(query, (size_t)b * 512 + t, isf);
  float s1 = v, s2 = v * v;
  for (int off = 32; off; off >>= 1) { s1 += __shfl_xor(s1, off); s2 += __shfl_xor(s2, off); }
  int wid = t >> 6, lane = t & 63;
  if (lane == 0) { red[wid * 2] = s1; red[wid * 2 + 1] = s2; }
  __syncthreads();
  if (t == 0) {
    float S = 0.f, SS = 0.f;
    for (int w = 0; w < 8; w++) { S += red[w * 2]; SS += red[w * 2 + 1]; }
    float mu = S / 512.f;
    stats[0] = mu; stats[1] = rsqrtf(SS / 512.f - mu * mu + 1e-5f);
  }
  __syncthreads();
  qln[(size_t)b * 512 + t] = (v - stats[0]) * stats[1] * ldx(g_q, t, isf) + ldx(be_q, t, isf);
}

// ---------------- kernel 2b: qr[b][j] += bq[j](cb==0) + sum_cslice qln*Wq ----------------
__global__ __launch_bounds__(512) void k_qproj(
    const float* __restrict__ qln, const void* __restrict__ Wq, const void* __restrict__ bq,
    float* __restrict__ qr, const int* __restrict__ flag) {
  int isf = flag[0];
  int cb = blockIdx.x;            // 8 c-slices of 64
  int j = threadIdx.x;
  __shared__ float qs[32 * 64];   // [b][cl]
  #pragma unroll
  for (int k = 0; k < 4; k++) {
    int e = j + 512 * k;          // 2048 = 32*64
    int b = e >> 6, cl = e & 63;
    qs[b * 64 + cl] = qln[(size_t)b * 512 + cb * 64 + cl];
  }
  __syncthreads();
  float acc[32];
  float bias = (cb == 0) ? ldx(bq, j, isf) : 0.f;
  #pragma unroll
  for (int b = 0; b < 32; b++) acc[b] = bias;
  for (int cl = 0; cl < 64; cl++) {
    float w = ldx(Wq, (size_t)(cb * 64 + cl) * 512 + j, isf);
    #pragma unroll
    for (int b = 0; b < 32; b++) acc[b] += qs[b * 64 + cl] * w;
  }
  #pragma unroll
  for (int b = 0; b < 32; b++) atomicAdd(qr + (size_t)b * 512 + j, acc[b]);
}

// ---------------- kernel 2c: u (bf16), c0 from qr ----------------
// grid(17): blocks 0..15 compute u for c-slice of 32; block 16 computes c0.
__global__ __launch_bounds__(256) void k_uprep(
    const float* __restrict__ qr, const void* __restrict__ Wkv, const void* __restrict__ bkv,
    u16* __restrict__ u_out, float* __restrict__ c0_out, const int* __restrict__ flag) {
  int isf = flag[0];
  int t = threadIdx.x;
  if (blockIdx.x == 16) {
    int b = t >> 3, n = t & 7;
    float acc = 0.f;
    for (int d = 0; d < 64; d++)
      acc += ldx(bkv, n * 64 + d, isf) * qr[(size_t)b * 512 + n * 64 + d];
    c0_out[b * 8 + n] = acc;
    return;
  }
  int cb = blockIdx.x;            // c-slice [cb*32, +32)
  __shared__ u16 qs[32 * 512];    // qr in bf16 [b][nd]
  #pragma unroll
  for (int k = 0; k < 64; k++) {
    int e = t + 256 * k;          // 16384
    qs[e] = f2b(qr[e]);
  }
  __syncthreads();
  int cl = t & 31, n = (t >> 5) & 7;
  int c = cb * 32 + cl;
  float acc[32];
  #pragma unroll
  for (int b = 0; b < 32; b++) acc[b] = 0.f;
  for (int d = 0; d < 64; d++) {
    float w = ldx(Wkv, (size_t)c * 1024 + n * 64 + d, isf);
    #pragma unroll
    for (int b = 0; b < 32; b++) acc[b] += b2f(qs[b * 512 + n * 64 + d]) * w;
  }
  #pragma unroll
  for (int b = 0; b < 32; b++) u_out[(size_t)(b * 512 + c) * 8 + n] = f2b(acc[b]);
}

// ---------------- kernel 3: fused m-GEMM + relu + LN + scores + r-atomics ----------------
// grid (64, 32), 512 thr (8 waves). One 64-row x 512-col tile per block.
#define LDA 40
#define LDB 40
__global__ __launch_bounds__(512) void k_main(
    const void* __restrict__ mem, const u16* __restrict__ WT, const void* __restrict__ b_in,
    const void* __restrict__ g_in, const void* __restrict__ be_in, const void* __restrict__ ior,
    const u16* __restrict__ u_in, const float* __restrict__ c0_in,
    float* __restrict__ r_acc, float* __restrict__ A_acc, const int* __restrict__ flag) {
  int isf = flag[0];
  int blk = blockIdx.x;           // 0..63 row tile
  int b   = blockIdx.y;           // 0..31
  int t = threadIdx.x;
  int w = t >> 6, lane = t & 63;
  int l15 = lane & 15, q = lane >> 4;

  // LDS 46080 B: Ab [0,5120), Bb [5120,46080)
  //   epilogue overlays in Bb: sc [5120,21504), rowred [21504,25600),
  //                            mu_rstd [25600,26112), a_lds [26112,28160)
  __shared__ __align__(16) char smem[46080];
  u16*  Ab      = (u16*)smem;
  u16*  Bb      = (u16*)(smem + 5120);
  float* sc     = (float*)(smem + 5120);
  float* rowred = (float*)(smem + 21504);
  float* mu_rstd= (float*)(smem + 25600);
  float* a_lds  = (float*)(smem + 26112);

  int colj[4];
  float gv[4], bev[4], binv[4];
  float uv[4][8];
  #pragma unroll
  for (int j = 0; j < 4; j++) {
    int col = w * 64 + j * 16 + l15;
    colj[j] = col;
    binv[j] = ldx(b_in, col, isf);
    gv[j]   = ldx(g_in, col, isf);
    bev[j]  = ldx(be_in, col, isf);
    uint4 p = *(const uint4*)(u_in + (size_t)(b * 512 + col) * 8);
    uv[j][0] = b2f((u16)(p.x & 0xffff)); uv[j][1] = b2f((u16)(p.x >> 16));
    uv[j][2] = b2f((u16)(p.y & 0xffff)); uv[j][3] = b2f((u16)(p.y >> 16));
    uv[j][4] = b2f((u16)(p.z & 0xffff)); uv[j][5] = b2f((u16)(p.z >> 16));
    uv[j][6] = b2f((u16)(p.w & 0xffff)); uv[j][7] = b2f((u16)(p.w >> 16));
  }

  int row0 = blk * 64;
  size_t memBase = ((size_t)b * 4096 + row0) * 512;

  f32x4 acc[4][4];
  #pragma unroll
  for (int i = 0; i < 4; i++)
    #pragma unroll
    for (int j = 0; j < 4; j++) { acc[i][j][0]=0.f; acc[i][j][1]=0.f; acc[i][j][2]=0.f; acc[i][j][3]=0.f; }

  for (int kk = 0; kk < 512; kk += 32) {
    __syncthreads();
    if (isf) {         // A tile 64x32 from f32
      int e = t * 4;
      int r = e >> 5, c = e & 31;
      float4 v = *(const float4*)((const float*)mem + memBase + (size_t)r * 512 + kk + c);
      union { u16 h[4]; uint2 u; } pk;
      pk.h[0] = f2b(v.x); pk.h[1] = f2b(v.y); pk.h[2] = f2b(v.z); pk.h[3] = f2b(v.w);
      *(uint2*)(Ab + r * LDA + c) = pk.u;
    } else if (t < 256) {
      int r = t >> 2, ch = t & 3;
      uint4 v = *(const uint4*)((const u16*)mem + memBase + (size_t)r * 512 + kk + ch * 8);
      *(uint4*)(Ab + r * LDA + ch * 8) = v;
    }
    #pragma unroll
    for (int s2 = 0; s2 < 4; s2++) {
      int e = t + 512 * s2;
      int j = e >> 2, ch = e & 3;
      uint4 v = *(const uint4*)(WT + (size_t)j * 512 + kk + ch * 8);
      *(uint4*)(Bb + j * LDB + ch * 8) = v;
    }
    __syncthreads();
    bf16x8 aF[4], bF[4];
    #pragma unroll
    for (int i = 0; i < 4; i++)
      aF[i] = *(const bf16x8*)(Ab + (i * 16 + l15) * LDA + q * 8);
    #pragma unroll
    for (int j = 0; j < 4; j++)
      bF[j] = *(const bf16x8*)(Bb + (w * 64 + j * 16 + l15) * LDB + q * 8);
    #pragma unroll
    for (int i = 0; i < 4; i++)
      #pragma unroll
      for (int j = 0; j < 4; j++)
        acc[i][j] = __builtin_amdgcn_mfma_f32_16x16x32_bf16(aF[i], bF[j], acc[i][j], 0, 0, 0);
  }
  __syncthreads();   // Bb dead; overlays begin

  // bias + relu
  #pragma unroll
  for (int i = 0; i < 4; i++)
    #pragma unroll
    for (int j = 0; j < 4; j++)
      #pragma unroll
      for (int r = 0; r < 4; r++) {
        float v = acc[i][j][r] + binv[j];
        acc[i][j][r] = v > 0.f ? v : 0.f;
      }
  // LN stats
  #pragma unroll
  for (int i = 0; i < 4; i++)
    #pragma unroll
    for (int r = 0; r < 4; r++) {
      float s  = acc[i][0][r] + acc[i][1][r] + acc[i][2][r] + acc[i][3][r];
      float ss = acc[i][0][r]*acc[i][0][r] + acc[i][1][r]*acc[i][1][r]
               + acc[i][2][r]*acc[i][2][r] + acc[i][3][r]*acc[i][3][r];
      #pragma unroll
      for (int m = 1; m < 16; m <<= 1) { s += __shfl_xor(s, m); ss += __shfl_xor(ss, m); }
      if (l15 == 0) {
        int row = i * 16 + q * 4 + r;
        rowred[(w * 64 + row) * 2]     = s;
        rowred[(w * 64 + row) * 2 + 1] = ss;
      }
    }
  __syncthreads();
  if (t < 64) {
    float S = 0.f, SS = 0.f;
    for (int w2 = 0; w2 < 8; w2++) { S += rowred[(w2 * 64 + t) * 2]; SS += rowred[(w2 * 64 + t) * 2 + 1]; }
    float mu = S / 512.f;
    mu_rstd[t * 2] = mu;
    mu_rstd[t * 2 + 1] = rsqrtf(SS / 512.f - mu * mu + 1e-5f);
  }
  __syncthreads();
  // apply LN
  #pragma unroll
  for (int i = 0; i < 4; i++)
    #pragma unroll
    for (int r = 0; r < 4; r++) {
      int row = i * 16 + q * 4 + r;
      float mu = mu_rstd[row * 2], rstd = mu_rstd[row * 2 + 1];
      #pragma unroll
      for (int j = 0; j < 4; j++)
        acc[i][j][r] = (acc[i][j][r] - mu) * rstd * gv[j] + bev[j];
    }

  // scores
  #pragma unroll
  for (int i = 0; i < 4; i++)
    #pragma unroll
    for (int r = 0; r < 4; r++) {
      int row = i * 16 + q * 4 + r;
      float p[8];
      #pragma unroll
      for (int n = 0; n < 8; n++) {
        float v = acc[i][0][r]*uv[0][n] + acc[i][1][r]*uv[1][n]
                + acc[i][2][r]*uv[2][n] + acc[i][3][r]*uv[3][n];
        #pragma unroll
        for (int m = 1; m < 16; m <<= 1) v += __shfl_xor(v, m);
        p[n] = v;
      }
      if (l15 == 0) {
        *(float4*)(sc + (w * 64 + row) * 8)     = make_float4(p[0], p[1], p[2], p[3]);
        *(float4*)(sc + (w * 64 + row) * 8 + 4) = make_float4(p[4], p[5], p[6], p[7]);
      }
    }
  __syncthreads();

  // a[row][n]
  {
    int row = t >> 3, n = t & 7;
    float ssum = 0.f;
    #pragma unroll
    for (int w2 = 0; w2 < 8; w2++) ssum += sc[(w2 * 64 + row) * 8 + n];
    float aval = (ssum + c0_in[b * 8 + n]) * 0.125f
               * ldx(ior, ((size_t)b * 8 + n) * 4096 + row0 + row, isf);
    a_lds[row * 8 + n] = aval;
  }
  __syncthreads();

  if (t < 8) {
    float s = 0.f;
    for (int row = 0; row < 64; row++) s += a_lds[row * 8 + t];
    atomicAdd(A_acc + b * 8 + t, s);
  }

  // r[n][col] over this tile's 64 rows -> atomics
  float rv[4][8];
  #pragma unroll
  for (int j = 0; j < 4; j++)
    #pragma unroll
    for (int n = 0; n < 8; n++) rv[j][n] = 0.f;
  #pragma unroll
  for (int i = 0; i < 4; i++)
    #pragma unroll
    for (int r = 0; r < 4; r++) {
      int row = i * 16 + q * 4 + r;
      const float* ap = a_lds + row * 8;
      float a0=ap[0],a1=ap[1],a2=ap[2],a3=ap[3],a4=ap[4],a5=ap[5],a6=ap[6],a7=ap[7];
      #pragma unroll
      for (int j = 0; j < 4; j++) {
        float m = acc[i][j][r];
        rv[j][0] += m*a0; rv[j][1] += m*a1; rv[j][2] += m*a2; rv[j][3] += m*a3;
        rv[j][4] += m*a4; rv[j][5] += m*a5; rv[j][6] += m*a6; rv[j][7] += m*a7;
      }
    }
  #pragma unroll
  for (int j = 0; j < 4; j++)
    #pragma unroll
    for (int n = 0; n < 8; n++) {
      float v = rv[j][n];
      v += __shfl_xor(v, 16);
      v += __shfl_xor(v, 32);
      rv[j][n] = v;
    }
  if (q == 0) {
    #pragma unroll
    for (int j = 0; j < 4; j++)
      #pragma unroll
      for (int n = 0; n < 8; n++)
        atomicAdd(r_acc + (size_t)(b * 8 + n) * 512 + colj[j], rv[j][n]);
  }
}

// ---------------- kernel 3b: x_acc[b][j] = A*bkv_v + sum_c r[b][n(j)][c]*Wv[c][j] ----------------
__global__ __launch_bounds__(512) void k_v(
    const float* __restrict__ r_acc, const float* __restrict__ A_acc,
    const void* __restrict__ Wkv, const void* __restrict__ bkv,
    float* __restrict__ x_acc, const int* __restrict__ flag) {
  int isf = flag[0];
  int cg = blockIdx.x;            // 8 c-slices of 64
  int j = threadIdx.x, n = j >> 6;
  float acc[32];
  #pragma unroll
  for (int b = 0; b < 32; b++)
    acc[b] = (cg == 0) ? A_acc[b * 8 + n] * ldx(bkv, 512 + j, isf) : 0.f;
  for (int cl = 0; cl < 64; cl++) {
    int c = cg * 64 + cl;
    float w = ldx(Wkv, (size_t)c * 1024 + 512 + j, isf);
    #pragma unroll
    for (int b = 0; b < 32; b++) acc[b] += r_acc[(size_t)(b * 8 + n) * 512 + c] * w;
  }
  #pragma unroll
  for (int b = 0; b < 32; b++) atomicAdd(x_acc + (size_t)b * 512 + j, acc[b]);
}

// ---------------- kernel 4: xrow = x_acc + query; LN -> xln; zero y_acc ----------------
__global__ __launch_bounds__(512) void k_mid(
    const float* __restrict__ x_acc, const void* __restrict__ query,
    const void* __restrict__ g_f, const void* __restrict__ be_f,
    float* __restrict__ xrow_ws, float* __restrict__ xln_ws,
    float* __restrict__ y_acc, const int* __restrict__ flag) {
  int isf = flag[0];
  int b = blockIdx.x, t = threadIdx.x;
  __shared__ float red[16];
  __shared__ float stats[2];
  y_acc[(size_t)b * 512 + t] = 0.f;   // r_acc region is dead; re-zero overlay
  float v = x_acc[(size_t)b * 512 + t] + ldx(query, (size_t)b * 512 + t, isf);
  xrow_ws[(size_t)b * 512 + t] = v;
  float s1 = v, s2 = v * v;
  for (int off = 32; off; off >>= 1) { s1 += __shfl_xor(s1, off); s2 += __shfl_xor(s2, off); }
  int wid = t >> 6, lane = t & 63;
  if (lane == 0) { red[wid * 2] = s1; red[wid * 2 + 1] = s2; }
  __syncthreads();
  if (t == 0) {
    float S = 0.f, SS = 0.f;
    for (int w = 0; w < 8; w++) { S += red[w * 2]; SS += red[w * 2 + 1]; }
    float mu = S / 512.f;
    stats[0] = mu; stats[1] = rsqrtf(SS / 512.f - mu * mu + 1e-5f);
  }
  __syncthreads();
  xln_ws[(size_t)b * 512 + t] = (v - stats[0]) * stats[1] * ldx(g_f, t, isf) + ldx(be_f, t, isf);
}

// ---------------- kernel 5: hdn = gelu(xln @ W1 + b1), weight-read-once ----------------
__global__ __launch_bounds__(512) void k_ffn1(
    const float* __restrict__ xln_ws, const void* __restrict__ W1, const void* __restrict__ b1,
    float* __restrict__ hdn_ws, const int* __restrict__ flag) {
  int isf = flag[0];
  int jb = blockIdx.x, bg = blockIdx.y, t = threadIdx.x;
  __shared__ float xl[8 * 512];   // [bi][c]
  #pragma unroll
  for (int k = 0; k < 8; k++) {
    int e = t + 512 * k;
    int bi = e >> 9, c = e & 511;
    xl[e] = xln_ws[(size_t)(bg * 8 + bi) * 512 + c];
  }
  __syncthreads();
  int j = jb * 512 + t;
  float bias = ldx(b1, j, isf);
  float acc[8];
  #pragma unroll
  for (int bi = 0; bi < 8; bi++) acc[bi] = bias;
  for (int c = 0; c < 512; c++) {
    float w = ldx(W1, (size_t)c * 2048 + j, isf);
    #pragma unroll
    for (int bi = 0; bi < 8; bi++) acc[bi] += xl[bi * 512 + c] * w;
  }
  #pragma unroll
  for (int bi = 0; bi < 8; bi++) {
    float v = acc[bi];
    hdn_ws[(size_t)(bg * 8 + bi) * 2048 + j] = 0.5f * v * (1.0f + erff(v * 0.70710678118654752f));
  }
}

// ---------------- kernel 6: y_acc += hdn @ W2 (c-sliced), weight-read-once ----------------
__global__ __launch_bounds__(512) void k_ffn2(
    const float* __restrict__ hdn_ws, const void* __restrict__ W2,
    float* __restrict__ y_acc, const int* __restrict__ flag) {
  int isf = flag[0];
  int cg = blockIdx.x, bg = blockIdx.y, t = threadIdx.x;
  __shared__ float hl[8 * 512];   // [bi][cl]
  #pragma unroll
  for (int k = 0; k < 8; k++) {
    int e = t + 512 * k;
    int bi = e >> 9, cl = e & 511;
    hl[e] = hdn_ws[(size_t)(bg * 8 + bi) * 2048 + cg * 512 + cl];
  }
  __syncthreads();
  int j = t;
  float acc[8];
  #pragma unroll
  for (int bi = 0; bi < 8; bi++) acc[bi] = 0.f;
  for (int cl = 0; cl < 512; cl++) {
    float w = ldx(W2, (size_t)(cg * 512 + cl) * 512 + j, isf);
    #pragma unroll
    for (int bi = 0; bi < 8; bi++) acc[bi] += hl[bi * 512 + cl] * w;
  }
  #pragma unroll
  for (int bi = 0; bi < 8; bi++)
    atomicAdd(y_acc + (size_t)(bg * 8 + bi) * 512 + j, acc[bi]);
}

// ---------------- kernel 7: out = cast(y_acc + b2 + xrow) ----------------
__global__ __launch_bounds__(512) void k_final(
    const float* __restrict__ y_acc, const void* __restrict__ b2v,
    const float* __restrict__ xrow_ws, void* __restrict__ out,
    const int* __restrict__ flag) {
  int isf = flag[0];
  int b = blockIdx.x, t = threadIdx.x;
  float v = y_acc[(size_t)b * 512 + t] + ldx(b2v, t, isf) + xrow_ws[(size_t)b * 512 + t];
  if (isf) ((float*)out)[b * 512 + t] = v;
  else     ((u16*)out)[b * 512 + t] = f2b(v);
}

extern "C" void kernel_launch(void* const* d_in, const int* in_sizes, int n_in,
                              void* d_out, int out_size, void* d_ws, size_t ws_size,
                              hipStream_t stream) {
  const void* query = d_in[0];
  const void* mem   = d_in[1];
  const void* ior   = d_in[2];
  const void* W_in  = d_in[3];
  const void* b_in  = d_in[4];
  const void* g_in  = d_in[5];
  const void* be_in = d_in[6];
  const void* Wq    = d_in[7];
  const void* bq    = d_in[8];
  const void* Wkv   = d_in[9];
  const void* bkv   = d_in[10];
  const void* W1    = d_in[11];
  const void* b1    = d_in[12];
  const void* W2    = d_in[13];
  const void* b2v   = d_in[14];
  const void* g_q   = d_in[15];
  const void* be_q  = d_in[16];
  const void* g_f   = d_in[17];
  const void* be_f  = d_in[18];

  // ws layout v5 (total 1,509,440 B; verified-safe bound 1,574,144 from R3)
  // flag    [0,       64)       zeroed then written by k_detect
  // A_acc   [64,      1088)     zeroed
  // x_acc   [1088,    66624)    zeroed
  // qr      [66624,   132160)   zeroed
  // r_acc   [132160,  656448)   zeroed (524288 B = 32*8*512 f32 -- the R4 bug fix)
  //   hdn_ws = 132160 (overlay; r dead after k_v; 262144 B)
  //   y_acc  = 394304 (overlay; zeroed by k_mid; 65536 B)
  // u16_ws  [656448,  918592)   bf16 u [b][c][n] (262144 B)
  //   xln_ws = 656448 (overlay; u dead after k_main)
  // c0_ws   [918592,  919616)
  // qln_ws  [919616,  985152)
  //   xrow_ws = 919616 (overlay; qln dead after k_qproj)
  // WT      [985152,  1509440)
  char* ws = (char*)d_ws;
  int*   flag   = (int*)ws;
  float* A_acc  = (float*)(ws + 64);
  float* x_acc  = (float*)(ws + 1088);
  float* qr     = (float*)(ws + 66624);
  float* r_acc  = (float*)(ws + 132160);
  float* hdn_ws = (float*)(ws + 132160);
  float* y_acc  = (float*)(ws + 394304);
  u16*   u_ws   = (u16*)(ws + 656448);
  float* xln_ws = (float*)(ws + 656448);
  float* c0_ws  = (float*)(ws + 918592);
  float* qln_ws = (float*)(ws + 919616);
  float* xrow_ws= (float*)(ws + 919616);
  u16*   WT     = (u16*)(ws + 985152);

  hipMemsetAsync(ws, 0, 656448, stream);  // flag,A_acc,x_acc,qr,r_acc
  k_detect<<<dim3(1), dim3(64), 0, stream>>>(query, flag);
  k_transpose<<<dim3(64), dim3(256), 0, stream>>>(W_in, WT, flag);
  k_qln<<<dim3(32), dim3(512), 0, stream>>>(query, g_q, be_q, qln_ws, flag);
  k_qproj<<<dim3(8), dim3(512), 0, stream>>>(qln_ws, Wq, bq, qr, flag);
  k_uprep<<<dim3(17), dim3(256), 0, stream>>>(qr, Wkv, bkv, u_ws, c0_ws, flag);
  k_main<<<dim3(64, 32), dim3(512), 0, stream>>>(mem, WT, b_in, g_in, be_in, ior,
                                                 u_ws, c0_ws, r_acc, A_acc, flag);
  k_v<<<dim3(8), dim3(512), 0, stream>>>(r_acc, A_acc, Wkv, bkv, x_acc, flag);
  k_mid<<<dim3(32), dim3(512), 0, stream>>>(x_acc, query, g_f, be_f, xrow_ws, xln_ws, y_acc, flag);
  k_ffn1<<<dim3(4, 4), dim3(512), 0, stream>>>(xln_ws, W1, b1, hdn_ws, flag);
  k_ffn2<<<dim3(4, 4), dim3(512), 0, stream>>>(hdn_ws, W2, y_acc, flag);
  k_final<<<dim3(32), dim3(512), 0, stream>>>(y_acc, b2v, xrow_ws, d_out, flag);
}